// Round 10
// baseline (951.896 us; speedup 1.0000x reference)
//
#include <hip/hip_runtime.h>
#include <hip/hip_bf16.h>
#include <hip/hip_fp16.h>

#define T_DIM 8192
#define H_DIM 3200
#define I_DIM 12800

typedef int v4i __attribute__((ext_vector_type(4)));
typedef _Float16 h8 __attribute__((ext_vector_type(8)));

__device__ __forceinline__ void gload16(const void* g, void* l) {
    __builtin_amdgcn_global_load_lds(
        (const __attribute__((address_space(1))) unsigned int*)g,
        (__attribute__((address_space(3))) unsigned int*)l, 16, 0, 0);
}

// ---------------- int32 -> int8 repack (memory-bound) ----------------
__global__ __launch_bounds__(256) void repack_kernel(const int* __restrict__ src,
                                                     unsigned int* __restrict__ dst,
                                                     long n4) {
    long i = (long)blockIdx.x * blockDim.x + threadIdx.x;
    long stride = (long)gridDim.x * blockDim.x;
    for (; i < n4; i += stride) {
        int4 v = ((const int4*)src)[i];
        dst[i] = (unsigned int)((v.x & 255) | ((v.y & 255) << 8) |
                                ((v.z & 255) << 16) | ((v.w & 255) << 24));
    }
}

// ---------------- i8 GEMM, C[M][N] = A[M][K] * B[N][K]^T ----------------
// R9 base (best: 379 us/GEMM, MfmaUtil 41.5%, 16 waves = 4/SIMD, per-wave
// 64x64, mfma_i32_16x16x64_i8, acc in AGPRs 64 + ~56 VGPR fits the 128-reg
// cap) with PAIR-PHASES: one phase per 128-B K-pair (2 halves) instead of
// per 64-B half. Effects: (1) barrier convergences per K halve (50 -> 25 for
// fc1) -- R4/R7 showed each barrier removal is worth 4-9%; (2) the vmcnt(0)
// gate is a free drain (the 4 pair-loads are issued at phase start and have
// a full ~2x-phase flight >> HBM latency before the gate); (3) unroll-by-2
// over pair parity makes every LDS slot offset a compile-time immediate and
// removes the per-phase clamp/slot VALU entirely (stage conditions are
// uniform scalar branches on p).
// Pair p occupies slots {0,1} (p even) or {2,3} (p odd) of the ring-of-4
// (4 x 16 KiB per operand, 128 KiB total). Phase p: { read even-half frags ;
// stage pair p+1 into the OPPOSITE slot-pair ; MFMA x16 ; read odd-half
// frags ; MFMA x16 ; vmcnt(0) ; ONE s_barrier }. Write-after-read safety
// (skew <= 1 phase): the opposite pair's readers (pair p-1) finished their
// ds_reads before crossing the previous barrier, which the stager has also
// crossed. K % 128 == 0 for both GEMMs (H=3200, I=12800).
// LDS dest of global_load_lds is LINEAR; XOR swizzle (16B chunk
// cc ^= (row>>1)&3) pre-applied to per-lane GLOBAL source and ds_read addrs
// (0-conflict, measured). strideA/strideB in BYTES. EPI=0: fp16 out;
// EPI=1: fp32 of fp16-rounded. fc2's N=3200 runs on 13 col-guarded tiles.
// No XCD swizzle (L3-resident regime).
template <int EPI>
__global__ __launch_bounds__(1024, 4) void gemm_i8_pair(
    const signed char* __restrict__ A, long strideA,
    const signed char* __restrict__ B, long strideB,
    int Ntrue, int K, int ldc,
    const float* __restrict__ rowscale, const float* __restrict__ colscale,
    const float* __restrict__ bias, void* __restrict__ Cout) {
    __shared__ signed char lds[131072];
    signed char* ldsA = lds;           // 4 units x 16384 B (256 rows x 64 B)
    signed char* ldsB = lds + 65536;   // 4 units x 16384 B

    const int tid = threadIdx.x;
    const int lane = tid & 63, wid = tid >> 6;
    const int wr = wid >> 2, wc = wid & 3;
    const int bm = blockIdx.x, bn = blockIdx.y;
    const long Arow0 = (long)bm * 256;
    const long Bcol0 = (long)bn * 256;

    // Staging: unit = 256 rows x 64 B = 1024 chunks of 16 B; thread handles
    // chunk tid. LDS dest linear (tid*16); swizzle folded into the per-lane
    // GLOBAL source chunk.
    const int r0 = tid >> 2;
    const int s0 = (((tid & 3) ^ ((r0 >> 1) & 3)) << 4);
    const signed char* Ag0 = A + (Arow0 + r0) * strideA + s0;
    const signed char* Bg0 = B + (Bcol0 + r0) * strideB + s0;
    const int d0 = tid * 16;

    const int NP = K >> 7;  // number of 128-B K-pairs (phases)

    // Stage pair p (halves 2p, 2p+1) into slot-pair at byte offset SB (0 or
    // 32768): even half -> SB, odd half -> SB+16384.
#define STAGE_PAIR(p, SB)                             \
    {                                                 \
        const long ko_ = (long)(p) << 7;              \
        gload16(Ag0 + ko_, ldsA + (SB) + d0);         \
        gload16(Bg0 + ko_, ldsB + (SB) + d0);         \
        gload16(Ag0 + ko_ + 64, ldsA + (SB) + 16384 + d0); \
        gload16(Bg0 + ko_ + 64, ldsB + (SB) + 16384 + d0); \
    }

    // Fragment read offsets: lane reads 16 B at (row, k-chunk q) -> LDS chunk
    // q ^ ((row>>1)&3); per-lane constant swz. Frag i lives at +i*1024.
    const int r = lane & 15, q = lane >> 4;
    const int swz = ((q ^ ((r >> 1) & 3)) << 4);
    const int aoff = (wr * 64 + r) * 64 + swz;  // + i*1024, i = 0..3
    const int boff = (wc * 64 + r) * 64 + swz;  // + n*1024, n = 0..3

    v4i acc[4][4] = {};

    // One half-K-step: read 8 frags at compile-time base HB, 16 MFMA.
#define HALF(HB)                                                            \
    {                                                                       \
        v4i af[4], bf[4];                                                   \
        _Pragma("unroll") for (int i = 0; i < 4; ++i)                       \
            af[i] = *(const v4i*)(ldsA + (HB) + aoff + i * 1024);           \
        _Pragma("unroll") for (int n = 0; n < 4; ++n)                       \
            bf[n] = *(const v4i*)(ldsB + (HB) + boff + n * 1024);           \
        __builtin_amdgcn_s_setprio(1);                                      \
        _Pragma("unroll") for (int m = 0; m < 4; ++m)                       \
            _Pragma("unroll") for (int n = 0; n < 4; ++n)                   \
                acc[m][n] = __builtin_amdgcn_mfma_i32_16x16x64_i8(          \
                    af[m], bf[n], acc[m][n], 0, 0, 0);                      \
        __builtin_amdgcn_s_setprio(0);                                      \
    }

    // Pair-phase at slot base SB (0/32768), staging pair pn into OTHER base.
#define PAIR_PHASE(SB, OTHER, DO_STAGE, pn)        \
    {                                              \
        if (DO_STAGE) STAGE_PAIR(pn, OTHER);       \
        HALF(SB);                                  \
        HALF((SB) + 16384);                        \
        asm volatile("s_waitcnt vmcnt(0)");        \
        __builtin_amdgcn_s_barrier();              \
    }

    // Prologue: stage pair 0 into slots {0,1}; drain; barrier.
    STAGE_PAIR(0, 0);
    asm volatile("s_waitcnt vmcnt(0)");
    __builtin_amdgcn_s_barrier();

    for (int p = 0; p < NP; p += 2) {
        PAIR_PHASE(0, 32768, p + 1 < NP, p + 1);
        if (p + 1 < NP) PAIR_PHASE(32768, 0, p + 2 < NP, p + 2);
    }

    // Epilogue: C/D layout col = lane&15, row = (lane>>4)*4 + reg.
    const int row0 = bm * 256 + wr * 64;
    const int col0 = bn * 256 + wc * 64;
    const int r4 = (lane >> 4) << 2, cl = lane & 15;
#pragma unroll
    for (int m = 0; m < 4; ++m) {
        const int rowb = row0 + m * 16 + r4;
        float rs[4];
#pragma unroll
        for (int rr = 0; rr < 4; ++rr) rs[rr] = rowscale[rowb + rr];
#pragma unroll
        for (int n = 0; n < 4; ++n) {
            const int col = col0 + n * 16 + cl;
            if (col < Ntrue) {
                const float cs = colscale[col];
                const float bs = bias[col];
#pragma unroll
                for (int rr = 0; rr < 4; ++rr) {
                    float v = (float)acc[m][n][rr];
                    v = __fmul_rn(v, rs[rr]);
                    v = __fmul_rn(v, cs);
                    v = __fadd_rn(v, bs);
                    _Float16 hh = (_Float16)v;  // reference rounds to fp16
                    const size_t idx = (size_t)(rowb + rr) * ldc + col;
                    if (EPI == 0) ((_Float16*)Cout)[idx] = hh;
                    else ((float*)Cout)[idx] = (float)hh;
                }
            }
        }
    }
#undef PAIR_PHASE
#undef HALF
#undef STAGE_PAIR
}

// -------- exact GELU + per-token dynamic int8 requant (in-place act_q) -------
__global__ __launch_bounds__(256) void gelu_quant(_Float16* __restrict__ fc1,
                                                  float* __restrict__ nscale) {
    __shared__ float gbuf[I_DIM];
    __shared__ float wmax[4];
    const int tid = threadIdx.x, lane = tid & 63, wid = tid >> 6;
    const long t = blockIdx.x;
    const h8* row = (const h8*)(fc1 + t * I_DIM);
    float lmax = 0.f;
    for (int c = tid; c < I_DIM / 8; c += 256) {
        h8 v = row[c];
#pragma unroll
        for (int j = 0; j < 8; ++j) {
            float x = (float)v[j];
            float e = erff(__fdiv_rn(x, 1.41421356237309504880f));
            float g = __fmul_rn(__fmul_rn(0.5f, x), __fadd_rn(1.0f, e));
            gbuf[c * 8 + j] = g;
            lmax = fmaxf(lmax, fabsf(g));
        }
    }
#pragma unroll
    for (int off = 32; off; off >>= 1) lmax = fmaxf(lmax, __shfl_xor(lmax, off, 64));
    if (lane == 0) wmax[wid] = lmax;
    __syncthreads();
    const float gmax = fmaxf(fmaxf(wmax[0], wmax[1]), fmaxf(wmax[2], wmax[3]));
    const float ns = gmax / 127.0f;
    if (tid == 0) nscale[t] = ns;
    unsigned long long* out = (unsigned long long*)(fc1 + t * I_DIM);  // in-place
    for (int c = tid; c < I_DIM / 8; c += 256) {
        unsigned long long pk = 0;
#pragma unroll
        for (int j = 0; j < 8; ++j) {
            float qv = rintf(__fdiv_rn(gbuf[c * 8 + j], ns));
            qv = fminf(fmaxf(qv, -127.f), 127.f);
            pk |= ((unsigned long long)(unsigned char)(signed char)(int)qv) << (8 * j);
        }
        out[c] = pk;
    }
}

extern "C" void kernel_launch(void* const* d_in, const int* in_sizes, int n_in,
                              void* d_out, int out_size, void* d_ws, size_t ws_size,
                              hipStream_t stream) {
    const int* hs = (const int*)d_in[0];        // [B,S,H] int8-in-int32
    const float* scale = (const float*)d_in[1]; // [T]
    const int* w1 = (const int*)d_in[2];        // [I,H]
    const float* w1s = (const float*)d_in[3];   // [I]
    const float* b1 = (const float*)d_in[4];    // [I]
    const int* w2 = (const int*)d_in[5];        // [H,I]
    const float* w2s = (const float*)d_in[6];   // [H]
    const float* b2 = (const float*)d_in[7];    // [H]

    char* ws = (char*)d_ws;
    signed char* xq = (signed char*)ws;                     // 26,214,400 B
    signed char* w1q = xq + (size_t)T_DIM * H_DIM;          // 40,960,000 B
    signed char* w2q = w1q + (size_t)I_DIM * H_DIM;         // 40,960,000 B
    _Float16* fc1h = (_Float16*)(w2q + (size_t)H_DIM * I_DIM);  // chunkT*I fp16
    const size_t fixed = (size_t)T_DIM * H_DIM + 2 * (size_t)I_DIM * H_DIM;

    // choose smallest chunk count whose workspace fits ws_size (deterministic)
    int nc = 1;
    while (nc < 16) {
        size_t need = fixed + ((size_t)T_DIM / nc) * I_DIM * 2 +
                      ((size_t)T_DIM / nc) * 4 + 256;
        if (need <= ws_size) break;
        nc <<= 1;
    }
    const int chunkT = T_DIM / nc;
    float* nscale = (float*)((char*)fc1h + (size_t)chunkT * I_DIM * 2);

    repack_kernel<<<2048, 256, 0, stream>>>(hs, (unsigned int*)xq, (long)T_DIM * H_DIM / 4);
    repack_kernel<<<2048, 256, 0, stream>>>(w1, (unsigned int*)w1q, (long)I_DIM * H_DIM / 4);
    repack_kernel<<<2048, 256, 0, stream>>>(w2, (unsigned int*)w2q, (long)H_DIM * I_DIM / 4);

    const int n2tiles = (H_DIM + 255) / 256;  // 13; last tile col-guarded
    for (int c = 0; c < nc; ++c) {
        const int t0 = c * chunkT;
        gemm_i8_pair<0><<<dim3(chunkT / 256, I_DIM / 256), 1024, 0, stream>>>(
            xq + (size_t)t0 * H_DIM, (long)H_DIM, w1q, (long)H_DIM,
            I_DIM, H_DIM, I_DIM,
            scale + t0, w1s, b1, (void*)fc1h);
        gelu_quant<<<chunkT, 256, 0, stream>>>(fc1h, nscale);
        gemm_i8_pair<1><<<dim3(chunkT / 256, n2tiles), 1024, 0, stream>>>(
            (const signed char*)fc1h, (long)I_DIM * 2, w2q, (long)I_DIM,
            H_DIM, I_DIM, H_DIM,
            nscale, w2s, b2,
            (void*)((float*)d_out + (size_t)t0 * H_DIM));
    }
}